// Round 5
// baseline (296.366 us; speedup 1.0000x reference)
//
#include <hip/hip_runtime.h>
#include <hip/hip_fp16.h>

#define NN 50000
#define NE 600000
#define KF 128      // IN_FEATS == H_FEATS
#define OC1 128
#define OC2 64
#define SCB 256
#define NSCB ((NN + SCB - 1) / SCB)   // 196

#define HB 32                          // histogram blocks
#define HCH ((NE + HB - 1) / HB)       // 18750 edges per block
#define HBIN 12500                     // bins per phase (50 KB LDS)

// ---------------- LDS-privatized degree histograms (no device atomics) ----------------
// 8 phases: {src x4 sub-ranges, dst x4 sub-ranges}. Each block histograms its own
// edge chunk into private LDS bins, then writes the partial histogram to global.
__launch_bounds__(256)
__global__ void hist_kernel(const int* __restrict__ src, const int* __restrict__ dst,
                            int* __restrict__ Hs, int* __restrict__ Hd) {
    __shared__ int bins[HBIN];
    const int b = blockIdx.x;
    const int e0 = b * HCH;
    const int e1 = min(e0 + HCH, NE);
#pragma unroll 1
    for (int phase = 0; phase < 8; phase++) {
        const int* key = (phase < 4) ? src : dst;
        int* H = (phase < 4) ? Hs : Hd;
        const int base = (phase & 3) * HBIN;
        for (int i = threadIdx.x; i < HBIN; i += 256) bins[i] = 0;
        __syncthreads();
        for (int e = e0 + threadIdx.x; e < e1; e += 256) {
            int v = key[e] - base;
            if ((unsigned)v < (unsigned)HBIN) atomicAdd(&bins[v], 1);
        }
        __syncthreads();
        for (int i = threadIdx.x; i < HBIN; i += 256) {
            int idx = base + i;
            if (idx < NN) H[(size_t)b * NN + idx] = bins[i];
        }
        __syncthreads();
    }
}

// reduce partial histograms -> deg_i (for scan) + both norms
__global__ void rednorm_kernel(const int* __restrict__ Hs, const int* __restrict__ Hd,
                               int* __restrict__ deg_i, float* __restrict__ nsrc,
                               float* __restrict__ ndst) {
    int v = blockIdx.x * blockDim.x + threadIdx.x;
    if (v >= NN) return;
    int so = 0, si = 0;
#pragma unroll
    for (int b = 0; b < HB; b++) {
        so += Hs[(size_t)b * NN + v];
        si += Hd[(size_t)b * NN + v];
    }
    deg_i[v] = si;
    nsrc[v] = rsqrtf(fmaxf((float)so, 1.0f));
    ndst[v] = rsqrtf(fmaxf((float)si, 1.0f));
}

// ---------------- hierarchical exclusive scan of in-degrees -> col_ptr ----------------
__launch_bounds__(SCB)
__global__ void scan_part(const int* __restrict__ deg, int* __restrict__ bsum) {
    __shared__ int s[SCB];
    int i = blockIdx.x * SCB + threadIdx.x;
    s[threadIdx.x] = (i < NN) ? deg[i] : 0;
    __syncthreads();
    for (int off = SCB / 2; off > 0; off >>= 1) {
        if (threadIdx.x < off) s[threadIdx.x] += s[threadIdx.x + off];
        __syncthreads();
    }
    if (threadIdx.x == 0) bsum[blockIdx.x] = s[0];
}

__launch_bounds__(SCB)
__global__ void scan_top(const int* __restrict__ bsum, int* __restrict__ boff) {
    __shared__ int s[SCB];
    const int tid = threadIdx.x;
    int v = (tid < NSCB) ? bsum[tid] : 0;
    s[tid] = v;
    __syncthreads();
    for (int off = 1; off < SCB; off <<= 1) {
        int t = (tid >= off) ? s[tid - off] : 0;
        __syncthreads();
        s[tid] += t;
        __syncthreads();
    }
    if (tid < NSCB) boff[tid] = s[tid] - v;   // exclusive
}

__launch_bounds__(SCB)
__global__ void scan_fin(const int* __restrict__ deg, const int* __restrict__ boff,
                         int* __restrict__ ptr, int* __restrict__ cursor) {
    __shared__ int s[SCB];
    const int tid = threadIdx.x;
    int i = blockIdx.x * SCB + tid;
    int v = (i < NN) ? deg[i] : 0;
    s[tid] = v;
    __syncthreads();
    for (int off = 1; off < SCB; off <<= 1) {
        int t = (tid >= off) ? s[tid - off] : 0;
        __syncthreads();
        s[tid] += t;
        __syncthreads();
    }
    if (i < NN) {
        int e = boff[blockIdx.x] + s[tid] - v;
        ptr[i] = e;
        cursor[i] = e;
    }
    if (i == 0) ptr[NN] = NE;
}

// fill dst-sorted edge list
__global__ void fill_kernel(const int* __restrict__ src, const int* __restrict__ dst,
                            int* __restrict__ cursor, int* __restrict__ esrc) {
    int e = blockIdx.x * blockDim.x + threadIdx.x;
    if (e >= NE) return;
    int p = atomicAdd(&cursor[dst[e]], 1);
    esrc[p] = src[e];
}

// ---------------- GEMM: g[r] = fp16( nsrc[r] * (A[r] @ W) ) ----------------
// A: [NN, KF] (f32 or f16)  W: [KF, OC] f32  g: [NN, OC] f16
template <int OC, typename AT>
__launch_bounds__(256)
__global__ void gemm_scale_kernel(const AT* __restrict__ A, const float* __restrict__ W,
                                  const float* __restrict__ nsrc, __half* __restrict__ g) {
    constexpr int CG = OC / 4;          // float4 column groups: 32 or 16
    constexpr int RT = 256 / CG;        // concurrent row-threads: 8 or 16
    constexpr int ROWS = 64;            // rows per block
    constexpr int RPT = ROWS / RT;      // rows per thread: 8 or 4
    constexpr int LDA4 = KF / 4 + 2;    // float4 stride 34: 16B-aligned, rows shift 8 banks
    __shared__ float4 As[ROWS][LDA4];

    const int tid = threadIdx.x;
    const int row0 = blockIdx.x * ROWS;

    for (int i = tid; i < ROWS * (KF / 4); i += 256) {
        int r = i >> 5;                 // KF/4 == 32
        int c = i & 31;
        float4 v = make_float4(0.f, 0.f, 0.f, 0.f);
        if (row0 + r < NN) {
            if constexpr (sizeof(AT) == 4) {
                v = reinterpret_cast<const float4*>(A + (size_t)(row0 + r) * KF)[c];
            } else {
                uint2 u = reinterpret_cast<const uint2*>(A + (size_t)(row0 + r) * KF)[c];
                __half2 ha = *reinterpret_cast<__half2*>(&u.x);
                __half2 hb = *reinterpret_cast<__half2*>(&u.y);
                float2 fa = __half22float2(ha);
                float2 fb = __half22float2(hb);
                v = make_float4(fa.x, fa.y, fb.x, fb.y);
            }
        }
        As[r][c] = v;
    }
    __syncthreads();

    const int cg = tid % CG;
    const int rt = tid / CG;
    const float4* Wp = reinterpret_cast<const float4*>(W) + cg;

    float4 acc[RPT];
#pragma unroll
    for (int i = 0; i < RPT; i++) acc[i] = make_float4(0.f, 0.f, 0.f, 0.f);

#pragma unroll 4
    for (int k4 = 0; k4 < KF / 4; k4++) {
        float4 w0 = Wp[(4 * k4 + 0) * CG];
        float4 w1 = Wp[(4 * k4 + 1) * CG];
        float4 w2 = Wp[(4 * k4 + 2) * CG];
        float4 w3 = Wp[(4 * k4 + 3) * CG];
#pragma unroll
        for (int rr = 0; rr < RPT; rr++) {
            float4 a = As[rt + rr * RT][k4];
            acc[rr].x = fmaf(a.x, w0.x, acc[rr].x);
            acc[rr].y = fmaf(a.x, w0.y, acc[rr].y);
            acc[rr].z = fmaf(a.x, w0.z, acc[rr].z);
            acc[rr].w = fmaf(a.x, w0.w, acc[rr].w);
            acc[rr].x = fmaf(a.y, w1.x, acc[rr].x);
            acc[rr].y = fmaf(a.y, w1.y, acc[rr].y);
            acc[rr].z = fmaf(a.y, w1.z, acc[rr].z);
            acc[rr].w = fmaf(a.y, w1.w, acc[rr].w);
            acc[rr].x = fmaf(a.z, w2.x, acc[rr].x);
            acc[rr].y = fmaf(a.z, w2.y, acc[rr].y);
            acc[rr].z = fmaf(a.z, w2.z, acc[rr].z);
            acc[rr].w = fmaf(a.z, w2.w, acc[rr].w);
            acc[rr].x = fmaf(a.w, w3.x, acc[rr].x);
            acc[rr].y = fmaf(a.w, w3.y, acc[rr].y);
            acc[rr].z = fmaf(a.w, w3.z, acc[rr].z);
            acc[rr].w = fmaf(a.w, w3.w, acc[rr].w);
        }
    }

#pragma unroll
    for (int rr = 0; rr < RPT; rr++) {
        int r = row0 + rt + rr * RT;
        if (r < NN) {
            float ns = nsrc[r];
            __half2 lo = __floats2half2_rn(acc[rr].x * ns, acc[rr].y * ns);
            __half2 hi = __floats2half2_rn(acc[rr].z * ns, acc[rr].w * ns);
            uint2 pk;
            pk.x = *reinterpret_cast<unsigned int*>(&lo);
            pk.y = *reinterpret_cast<unsigned int*>(&hi);
            reinterpret_cast<uint2*>(g + (size_t)r * OC)[cg] = pk;
        }
    }
}

// ---------------- gather (OC=128): h1[d] = fp16(relu(ndst*sum g[esrc] + b)) ----------------
// one wave per node, lane owns 2 feats (half2), 8-edge unroll
__launch_bounds__(256)
__global__ void gather128_kernel(const __half2* __restrict__ g, const int* __restrict__ ptr,
                                 const int* __restrict__ esrc, const float* __restrict__ ndst,
                                 const float* __restrict__ b, __half2* __restrict__ h1) {
    const int node = blockIdx.x * 4 + (threadIdx.x >> 6);
    if (node >= NN) return;
    const int lane = threadIdx.x & 63;
    const int lo = ptr[node];
    const int hi = ptr[node + 1];
    const float nd = ndst[node];

    float2 a[8];
#pragma unroll
    for (int i = 0; i < 8; i++) a[i] = make_float2(0.f, 0.f);

    int e = lo;
    for (; e + 7 < hi; e += 8) {
        int s[8];
#pragma unroll
        for (int i = 0; i < 8; i++) s[i] = esrc[e + i];
#pragma unroll
        for (int i = 0; i < 8; i++) {
            float2 v = __half22float2(g[(size_t)s[i] * 64 + lane]);
            a[i].x += v.x; a[i].y += v.y;
        }
    }
    for (; e < hi; e++) {
        float2 v = __half22float2(g[(size_t)esrc[e] * 64 + lane]);
        a[0].x += v.x; a[0].y += v.y;
    }
#pragma unroll
    for (int i = 1; i < 8; i++) { a[0].x += a[i].x; a[0].y += a[i].y; }

    float2 bb = reinterpret_cast<const float2*>(b)[lane];
    float ox = fmaxf(fmaf(a[0].x, nd, bb.x), 0.f);
    float oy = fmaxf(fmaf(a[0].y, nd, bb.y), 0.f);
    h1[(size_t)node * 64 + lane] = __floats2half2_rn(ox, oy);
}

// ---------------- gather (OC=64): out[d] = f32(ndst*sum g[esrc] + b) ----------------
// one wave per node; half-wave per edge (lane&31 owns 2 feats), 4x unroll per half
__launch_bounds__(256)
__global__ void gather64_kernel(const __half2* __restrict__ g, const int* __restrict__ ptr,
                                const int* __restrict__ esrc, const float* __restrict__ ndst,
                                const float* __restrict__ b, float* __restrict__ out) {
    const int node = blockIdx.x * 4 + (threadIdx.x >> 6);
    if (node >= NN) return;
    const int lane = threadIdx.x & 63;
    const int l32 = lane & 31;
    const int half_id = lane >> 5;
    const int lo = ptr[node];
    const int hi = ptr[node + 1];
    const float nd = ndst[node];

    float2 a[4];
#pragma unroll
    for (int i = 0; i < 4; i++) a[i] = make_float2(0.f, 0.f);

    int e = lo + half_id;
    for (; e + 6 < hi; e += 8) {
        int s[4];
#pragma unroll
        for (int i = 0; i < 4; i++) s[i] = esrc[e + 2 * i];
#pragma unroll
        for (int i = 0; i < 4; i++) {
            float2 v = __half22float2(g[(size_t)s[i] * 32 + l32]);
            a[i].x += v.x; a[i].y += v.y;
        }
    }
    for (; e < hi; e += 2) {
        float2 v = __half22float2(g[(size_t)esrc[e] * 32 + l32]);
        a[0].x += v.x; a[0].y += v.y;
    }
#pragma unroll
    for (int i = 1; i < 4; i++) { a[0].x += a[i].x; a[0].y += a[i].y; }

    // combine the two half-wave partial sums
    a[0].x += __shfl_xor(a[0].x, 32);
    a[0].y += __shfl_xor(a[0].y, 32);
    if (half_id == 0) {
        float2 bb = reinterpret_cast<const float2*>(b)[l32];
        float2 o = make_float2(fmaf(a[0].x, nd, bb.x), fmaf(a[0].y, nd, bb.y));
        reinterpret_cast<float2*>(out + (size_t)node * 64)[l32] = o;
    }
}

extern "C" void kernel_launch(void* const* d_in, const int* in_sizes, int n_in,
                              void* d_out, int out_size, void* d_ws, size_t ws_size,
                              hipStream_t stream) {
    const float* x  = (const float*)d_in[0];   // [NN, 128]
    const float* W1 = (const float*)d_in[1];   // [128, 128]
    const float* b1 = (const float*)d_in[2];   // [128]
    const float* W2 = (const float*)d_in[3];   // [128, 64]
    const float* b2 = (const float*)d_in[4];   // [64]
    const int*   src = (const int*)d_in[5];    // [NE]
    const int*   dst = (const int*)d_in[6];    // [NE]
    float* out = (float*)d_out;                // [NN, 64]

    float*  nsrc = (float*)d_ws;                     // NN
    float*  ndst = nsrc + NN;                        // NN
    __half* g    = (__half*)(ndst + NN);             // NN*128 f16 (layer 2 uses NN*64)
    __half* h1   = g + (size_t)NN * KF;              // NN*128 f16
    int* deg_i  = (int*)(h1 + (size_t)NN * KF);      // NN
    int* ptr    = deg_i + NN;                        // NN+1
    int* cursor = ptr + NN + 1;                      // NN
    int* esrc   = cursor + NN;                       // NE
    int* bsum   = esrc + NE;                         // NSCB
    int* boff   = bsum + NSCB;                       // NSCB
    int* Hs     = boff + NSCB;                       // HB*NN
    int* Hd     = Hs + (size_t)HB * NN;              // HB*NN

    // degrees (privatized LDS histogram) -> norms, CSC build
    hist_kernel<<<HB, 256, 0, stream>>>(src, dst, Hs, Hd);
    rednorm_kernel<<<(NN + 255) / 256, 256, 0, stream>>>(Hs, Hd, deg_i, nsrc, ndst);
    scan_part<<<NSCB, SCB, 0, stream>>>(deg_i, bsum);
    scan_top<<<1, SCB, 0, stream>>>(bsum, boff);
    scan_fin<<<NSCB, SCB, 0, stream>>>(deg_i, boff, ptr, cursor);
    fill_kernel<<<(NE + 255) / 256, 256, 0, stream>>>(src, dst, cursor, esrc);

    // layer 1: g = fp16(nsrc * (x @ W1)); h1 = fp16(relu(ndst * gather(g) + b1))
    gemm_scale_kernel<OC1, float><<<(NN + 63) / 64, 256, 0, stream>>>(x, W1, nsrc, g);
    gather128_kernel<<<(NN + 3) / 4, 256, 0, stream>>>((const __half2*)g, ptr, esrc, ndst, b1,
                                                       (__half2*)h1);

    // layer 2: g = fp16(nsrc * (h1 @ W2)); out = ndst * gather(g) + b2
    gemm_scale_kernel<OC2, __half><<<(NN + 63) / 64, 256, 0, stream>>>(h1, W2, nsrc, g);
    gather64_kernel<<<(NN + 3) / 4, 256, 0, stream>>>((const __half2*)g, ptr, esrc, ndst, b2, out);
}

// Round 6
// 182.774 us; speedup vs baseline: 1.6215x; 1.6215x over previous
//
#include <hip/hip_runtime.h>
#include <hip/hip_fp16.h>

#define NN 50000
#define NE 600000
#define KF 128      // IN_FEATS == H_FEATS
#define OC1 128
#define OC2 64
#define SCB 256
#define NSCB ((NN + SCB - 1) / SCB)   // 196

#define HBLK 64                        // histogram blocks per phase (src / dst)
#define HCH ((NE + HBLK - 1) / HBLK)   // 9375 edges per block (< 65536: 16-bit safe)
#define HP (NN / 2)                    // 25000 packed bins (two 16-bit counts per int)

// ---------------- full-range packed-16-bit LDS histogram ----------------
// grid = 2*HBLK: blocks [0,HBLK) histogram src, [HBLK,2*HBLK) histogram dst.
// Each block: zero 100 KB LDS, count its 9375-edge chunk with packed LDS
// atomics, write the partial histogram coalesced. No device atomics.
__launch_bounds__(256)
__global__ void hist16_kernel(const int* __restrict__ src, const int* __restrict__ dst,
                              int* __restrict__ Hs, int* __restrict__ Hd) {
    __shared__ int bins[HP];
    const int b = blockIdx.x;
    const bool is_src = (b < HBLK);
    const int bb = is_src ? b : b - HBLK;
    const int* key = is_src ? src : dst;
    int* H = is_src ? Hs : Hd;
    const int e0 = bb * HCH;
    const int e1 = min(e0 + HCH, NE);

    for (int i = threadIdx.x; i < HP; i += 256) bins[i] = 0;
    __syncthreads();
    for (int e = e0 + threadIdx.x; e < e1; e += 256) {
        int v = key[e];
        atomicAdd(&bins[v >> 1], 1 << ((v & 1) * 16));
    }
    __syncthreads();
    int* out = H + (size_t)bb * HP;
    for (int i = threadIdx.x; i < HP; i += 256) out[i] = bins[i];
}

// reduce partials (unpack 16-bit halves) -> deg_i + both norms
__global__ void rednorm_kernel(const int* __restrict__ Hs, const int* __restrict__ Hd,
                               int* __restrict__ deg_i, float* __restrict__ nsrc,
                               float* __restrict__ ndst) {
    int p = blockIdx.x * blockDim.x + threadIdx.x;   // packed pair index
    if (p >= HP) return;
    int so0 = 0, so1 = 0, si0 = 0, si1 = 0;
#pragma unroll 4
    for (int b = 0; b < HBLK; b++) {
        int hs = Hs[(size_t)b * HP + p];
        int hd = Hd[(size_t)b * HP + p];
        so0 += hs & 0xFFFF; so1 += hs >> 16;   // counts <= 9375: no sign issues
        si0 += hd & 0xFFFF; si1 += hd >> 16;
    }
    reinterpret_cast<int2*>(deg_i)[p] = make_int2(si0, si1);
    reinterpret_cast<float2*>(nsrc)[p] =
        make_float2(rsqrtf(fmaxf((float)so0, 1.f)), rsqrtf(fmaxf((float)so1, 1.f)));
    reinterpret_cast<float2*>(ndst)[p] =
        make_float2(rsqrtf(fmaxf((float)si0, 1.f)), rsqrtf(fmaxf((float)si1, 1.f)));
}

// ---------------- hierarchical exclusive scan of in-degrees -> col_ptr ----------------
__launch_bounds__(SCB)
__global__ void scan_part(const int* __restrict__ deg, int* __restrict__ bsum) {
    __shared__ int s[SCB];
    int i = blockIdx.x * SCB + threadIdx.x;
    s[threadIdx.x] = (i < NN) ? deg[i] : 0;
    __syncthreads();
    for (int off = SCB / 2; off > 0; off >>= 1) {
        if (threadIdx.x < off) s[threadIdx.x] += s[threadIdx.x + off];
        __syncthreads();
    }
    if (threadIdx.x == 0) bsum[blockIdx.x] = s[0];
}

__launch_bounds__(SCB)
__global__ void scan_top(const int* __restrict__ bsum, int* __restrict__ boff) {
    __shared__ int s[SCB];
    const int tid = threadIdx.x;
    int v = (tid < NSCB) ? bsum[tid] : 0;
    s[tid] = v;
    __syncthreads();
    for (int off = 1; off < SCB; off <<= 1) {
        int t = (tid >= off) ? s[tid - off] : 0;
        __syncthreads();
        s[tid] += t;
        __syncthreads();
    }
    if (tid < NSCB) boff[tid] = s[tid] - v;   // exclusive
}

__launch_bounds__(SCB)
__global__ void scan_fin(const int* __restrict__ deg, const int* __restrict__ boff,
                         int* __restrict__ ptr, int* __restrict__ cursor) {
    __shared__ int s[SCB];
    const int tid = threadIdx.x;
    int i = blockIdx.x * SCB + tid;
    int v = (i < NN) ? deg[i] : 0;
    s[tid] = v;
    __syncthreads();
    for (int off = 1; off < SCB; off <<= 1) {
        int t = (tid >= off) ? s[tid - off] : 0;
        __syncthreads();
        s[tid] += t;
        __syncthreads();
    }
    if (i < NN) {
        int e = boff[blockIdx.x] + s[tid] - v;
        ptr[i] = e;
        cursor[i] = e;
    }
    if (i == 0) ptr[NN] = NE;
}

// fill dst-sorted edge list
__global__ void fill_kernel(const int* __restrict__ src, const int* __restrict__ dst,
                            int* __restrict__ cursor, int* __restrict__ esrc) {
    int e = blockIdx.x * blockDim.x + threadIdx.x;
    if (e >= NE) return;
    int p = atomicAdd(&cursor[dst[e]], 1);
    esrc[p] = src[e];
}

// ---------------- GEMM: g[r] = fp16( nsrc[r] * (A[r] @ W) ) ----------------
// A: [NN, KF] (f32 or f16)  W: [KF, OC] f32  g: [NN, OC] f16
template <int OC, typename AT>
__launch_bounds__(256)
__global__ void gemm_scale_kernel(const AT* __restrict__ A, const float* __restrict__ W,
                                  const float* __restrict__ nsrc, __half* __restrict__ g) {
    constexpr int CG = OC / 4;          // float4 column groups: 32 or 16
    constexpr int RT = 256 / CG;        // concurrent row-threads: 8 or 16
    constexpr int ROWS = 64;            // rows per block
    constexpr int RPT = ROWS / RT;      // rows per thread: 8 or 4
    constexpr int LDA4 = KF / 4 + 2;    // float4 stride 34: 16B-aligned, rows shift 8 banks
    __shared__ float4 As[ROWS][LDA4];

    const int tid = threadIdx.x;
    const int row0 = blockIdx.x * ROWS;

    for (int i = tid; i < ROWS * (KF / 4); i += 256) {
        int r = i >> 5;                 // KF/4 == 32
        int c = i & 31;
        float4 v = make_float4(0.f, 0.f, 0.f, 0.f);
        if (row0 + r < NN) {
            if constexpr (sizeof(AT) == 4) {
                v = reinterpret_cast<const float4*>(A + (size_t)(row0 + r) * KF)[c];
            } else {
                uint2 u = reinterpret_cast<const uint2*>(A + (size_t)(row0 + r) * KF)[c];
                __half2 ha = *reinterpret_cast<__half2*>(&u.x);
                __half2 hb = *reinterpret_cast<__half2*>(&u.y);
                float2 fa = __half22float2(ha);
                float2 fb = __half22float2(hb);
                v = make_float4(fa.x, fa.y, fb.x, fb.y);
            }
        }
        As[r][c] = v;
    }
    __syncthreads();

    const int cg = tid % CG;
    const int rt = tid / CG;
    const float4* Wp = reinterpret_cast<const float4*>(W) + cg;

    float4 acc[RPT];
#pragma unroll
    for (int i = 0; i < RPT; i++) acc[i] = make_float4(0.f, 0.f, 0.f, 0.f);

#pragma unroll 4
    for (int k4 = 0; k4 < KF / 4; k4++) {
        float4 w0 = Wp[(4 * k4 + 0) * CG];
        float4 w1 = Wp[(4 * k4 + 1) * CG];
        float4 w2 = Wp[(4 * k4 + 2) * CG];
        float4 w3 = Wp[(4 * k4 + 3) * CG];
#pragma unroll
        for (int rr = 0; rr < RPT; rr++) {
            float4 a = As[rt + rr * RT][k4];
            acc[rr].x = fmaf(a.x, w0.x, acc[rr].x);
            acc[rr].y = fmaf(a.x, w0.y, acc[rr].y);
            acc[rr].z = fmaf(a.x, w0.z, acc[rr].z);
            acc[rr].w = fmaf(a.x, w0.w, acc[rr].w);
            acc[rr].x = fmaf(a.y, w1.x, acc[rr].x);
            acc[rr].y = fmaf(a.y, w1.y, acc[rr].y);
            acc[rr].z = fmaf(a.y, w1.z, acc[rr].z);
            acc[rr].w = fmaf(a.y, w1.w, acc[rr].w);
            acc[rr].x = fmaf(a.z, w2.x, acc[rr].x);
            acc[rr].y = fmaf(a.z, w2.y, acc[rr].y);
            acc[rr].z = fmaf(a.z, w2.z, acc[rr].z);
            acc[rr].w = fmaf(a.z, w2.w, acc[rr].w);
            acc[rr].x = fmaf(a.w, w3.x, acc[rr].x);
            acc[rr].y = fmaf(a.w, w3.y, acc[rr].y);
            acc[rr].z = fmaf(a.w, w3.z, acc[rr].z);
            acc[rr].w = fmaf(a.w, w3.w, acc[rr].w);
        }
    }

#pragma unroll
    for (int rr = 0; rr < RPT; rr++) {
        int r = row0 + rt + rr * RT;
        if (r < NN) {
            float ns = nsrc[r];
            __half2 lo = __floats2half2_rn(acc[rr].x * ns, acc[rr].y * ns);
            __half2 hi = __floats2half2_rn(acc[rr].z * ns, acc[rr].w * ns);
            uint2 pk;
            pk.x = *reinterpret_cast<unsigned int*>(&lo);
            pk.y = *reinterpret_cast<unsigned int*>(&hi);
            reinterpret_cast<uint2*>(g + (size_t)r * OC)[cg] = pk;
        }
    }
}

// ---------------- gather (OC=128): h1[d] = fp16(relu(ndst*sum g[esrc] + b)) ----------------
// one wave per node, lane owns 2 feats (half2), 8-edge unroll
__launch_bounds__(256)
__global__ void gather128_kernel(const __half2* __restrict__ g, const int* __restrict__ ptr,
                                 const int* __restrict__ esrc, const float* __restrict__ ndst,
                                 const float* __restrict__ b, __half2* __restrict__ h1) {
    const int node = blockIdx.x * 4 + (threadIdx.x >> 6);
    if (node >= NN) return;
    const int lane = threadIdx.x & 63;
    const int lo = ptr[node];
    const int hi = ptr[node + 1];
    const float nd = ndst[node];

    float2 a[8];
#pragma unroll
    for (int i = 0; i < 8; i++) a[i] = make_float2(0.f, 0.f);

    int e = lo;
    for (; e + 7 < hi; e += 8) {
        int s[8];
#pragma unroll
        for (int i = 0; i < 8; i++) s[i] = esrc[e + i];
#pragma unroll
        for (int i = 0; i < 8; i++) {
            float2 v = __half22float2(g[(size_t)s[i] * 64 + lane]);
            a[i].x += v.x; a[i].y += v.y;
        }
    }
    for (; e < hi; e++) {
        float2 v = __half22float2(g[(size_t)esrc[e] * 64 + lane]);
        a[0].x += v.x; a[0].y += v.y;
    }
#pragma unroll
    for (int i = 1; i < 8; i++) { a[0].x += a[i].x; a[0].y += a[i].y; }

    float2 bb = reinterpret_cast<const float2*>(b)[lane];
    float ox = fmaxf(fmaf(a[0].x, nd, bb.x), 0.f);
    float oy = fmaxf(fmaf(a[0].y, nd, bb.y), 0.f);
    h1[(size_t)node * 64 + lane] = __floats2half2_rn(ox, oy);
}

// ---------------- gather (OC=64): out[d] = f32(ndst*sum g[esrc] + b) ----------------
// one wave per node; half-wave per edge (lane&31 owns 2 feats), 4x unroll per half
__launch_bounds__(256)
__global__ void gather64_kernel(const __half2* __restrict__ g, const int* __restrict__ ptr,
                                const int* __restrict__ esrc, const float* __restrict__ ndst,
                                const float* __restrict__ b, float* __restrict__ out) {
    const int node = blockIdx.x * 4 + (threadIdx.x >> 6);
    if (node >= NN) return;
    const int lane = threadIdx.x & 63;
    const int l32 = lane & 31;
    const int half_id = lane >> 5;
    const int lo = ptr[node];
    const int hi = ptr[node + 1];
    const float nd = ndst[node];

    float2 a[4];
#pragma unroll
    for (int i = 0; i < 4; i++) a[i] = make_float2(0.f, 0.f);

    int e = lo + half_id;
    for (; e + 6 < hi; e += 8) {
        int s[4];
#pragma unroll
        for (int i = 0; i < 4; i++) s[i] = esrc[e + 2 * i];
#pragma unroll
        for (int i = 0; i < 4; i++) {
            float2 v = __half22float2(g[(size_t)s[i] * 32 + l32]);
            a[i].x += v.x; a[i].y += v.y;
        }
    }
    for (; e < hi; e += 2) {
        float2 v = __half22float2(g[(size_t)esrc[e] * 32 + l32]);
        a[0].x += v.x; a[0].y += v.y;
    }
#pragma unroll
    for (int i = 1; i < 4; i++) { a[0].x += a[i].x; a[0].y += a[i].y; }

    // combine the two half-wave partial sums
    a[0].x += __shfl_xor(a[0].x, 32);
    a[0].y += __shfl_xor(a[0].y, 32);
    if (half_id == 0) {
        float2 bb = reinterpret_cast<const float2*>(b)[l32];
        float2 o = make_float2(fmaf(a[0].x, nd, bb.x), fmaf(a[0].y, nd, bb.y));
        reinterpret_cast<float2*>(out + (size_t)node * 64)[l32] = o;
    }
}

extern "C" void kernel_launch(void* const* d_in, const int* in_sizes, int n_in,
                              void* d_out, int out_size, void* d_ws, size_t ws_size,
                              hipStream_t stream) {
    const float* x  = (const float*)d_in[0];   // [NN, 128]
    const float* W1 = (const float*)d_in[1];   // [128, 128]
    const float* b1 = (const float*)d_in[2];   // [128]
    const float* W2 = (const float*)d_in[3];   // [128, 64]
    const float* b2 = (const float*)d_in[4];   // [64]
    const int*   src = (const int*)d_in[5];    // [NE]
    const int*   dst = (const int*)d_in[6];    // [NE]
    float* out = (float*)d_out;                // [NN, 64]

    float*  nsrc = (float*)d_ws;                     // NN
    float*  ndst = nsrc + NN;                        // NN
    __half* g    = (__half*)(ndst + NN);             // NN*128 f16 (layer 2 uses NN*64)
    __half* h1   = g + (size_t)NN * KF;              // NN*128 f16
    int* deg_i  = (int*)(h1 + (size_t)NN * KF);      // NN
    int* ptr    = deg_i + NN;                        // NN+1
    int* cursor = ptr + NN + 1;                      // NN
    int* esrc   = cursor + NN;                       // NE
    int* bsum   = esrc + NE;                         // NSCB
    int* boff   = bsum + NSCB;                       // NSCB
    int* Hs     = boff + NSCB;                       // HBLK*HP  (6.4 MB)
    int* Hd     = Hs + (size_t)HBLK * HP;            // HBLK*HP  (6.4 MB)

    // degrees (packed 16-bit LDS histogram, no device atomics) -> norms, CSC build
    hist16_kernel<<<2 * HBLK, 256, 0, stream>>>(src, dst, Hs, Hd);
    rednorm_kernel<<<(HP + 255) / 256, 256, 0, stream>>>(Hs, Hd, deg_i, nsrc, ndst);
    scan_part<<<NSCB, SCB, 0, stream>>>(deg_i, bsum);
    scan_top<<<1, SCB, 0, stream>>>(bsum, boff);
    scan_fin<<<NSCB, SCB, 0, stream>>>(deg_i, boff, ptr, cursor);
    fill_kernel<<<(NE + 255) / 256, 256, 0, stream>>>(src, dst, cursor, esrc);

    // layer 1: g = fp16(nsrc * (x @ W1)); h1 = fp16(relu(ndst * gather(g) + b1))
    gemm_scale_kernel<OC1, float><<<(NN + 63) / 64, 256, 0, stream>>>(x, W1, nsrc, g);
    gather128_kernel<<<(NN + 3) / 4, 256, 0, stream>>>((const __half2*)g, ptr, esrc, ndst, b1,
                                                       (__half2*)h1);

    // layer 2: g = fp16(nsrc * (h1 @ W2)); out = ndst * gather(g) + b2
    gemm_scale_kernel<OC2, __half><<<(NN + 63) / 64, 256, 0, stream>>>(h1, W2, nsrc, g);
    gather64_kernel<<<(NN + 3) / 4, 256, 0, stream>>>((const __half2*)g, ptr, esrc, ndst, b2, out);
}

// Round 7
// 176.474 us; speedup vs baseline: 1.6794x; 1.0357x over previous
//
#include <hip/hip_runtime.h>
#include <hip/hip_fp16.h>

#define NN 50000
#define NE 600000
#define KF 128      // IN_FEATS == H_FEATS
#define OC1 128
#define OC2 64
#define SCB 256
#define NSCB ((NN + SCB - 1) / SCB)   // 196

#define HBLK 64                        // histogram blocks per phase (src / dst)
#define HCH ((NE + HBLK - 1) / HBLK)   // 9375 edges per block (< 65536: 16-bit safe)
#define HP (NN / 2)                    // 25000 packed bins (two 16-bit counts per int)

typedef _Float16 half8 __attribute__((ext_vector_type(8)));
typedef float floatx4 __attribute__((ext_vector_type(4)));

// ---------------- full-range packed-16-bit LDS histogram ----------------
__launch_bounds__(256)
__global__ void hist16_kernel(const int* __restrict__ src, const int* __restrict__ dst,
                              int* __restrict__ Hs, int* __restrict__ Hd) {
    __shared__ int bins[HP];
    const int b = blockIdx.x;
    const bool is_src = (b < HBLK);
    const int bb = is_src ? b : b - HBLK;
    const int* key = is_src ? src : dst;
    int* H = is_src ? Hs : Hd;
    const int e0 = bb * HCH;
    const int e1 = min(e0 + HCH, NE);

    for (int i = threadIdx.x; i < HP; i += 256) bins[i] = 0;
    __syncthreads();
    for (int e = e0 + threadIdx.x; e < e1; e += 256) {
        int v = key[e];
        atomicAdd(&bins[v >> 1], 1 << ((v & 1) * 16));
    }
    __syncthreads();
    int* out = H + (size_t)bb * HP;
    for (int i = threadIdx.x; i < HP; i += 256) out[i] = bins[i];
}

// reduce partials (unpack 16-bit halves) -> deg_i + both norms
__global__ void rednorm_kernel(const int* __restrict__ Hs, const int* __restrict__ Hd,
                               int* __restrict__ deg_i, float* __restrict__ nsrc,
                               float* __restrict__ ndst) {
    int p = blockIdx.x * blockDim.x + threadIdx.x;   // packed pair index
    if (p >= HP) return;
    int so0 = 0, so1 = 0, si0 = 0, si1 = 0;
#pragma unroll 4
    for (int b = 0; b < HBLK; b++) {
        int hs = Hs[(size_t)b * HP + p];
        int hd = Hd[(size_t)b * HP + p];
        so0 += hs & 0xFFFF; so1 += hs >> 16;
        si0 += hd & 0xFFFF; si1 += hd >> 16;
    }
    reinterpret_cast<int2*>(deg_i)[p] = make_int2(si0, si1);
    reinterpret_cast<float2*>(nsrc)[p] =
        make_float2(rsqrtf(fmaxf((float)so0, 1.f)), rsqrtf(fmaxf((float)so1, 1.f)));
    reinterpret_cast<float2*>(ndst)[p] =
        make_float2(rsqrtf(fmaxf((float)si0, 1.f)), rsqrtf(fmaxf((float)si1, 1.f)));
}

// ---------------- hierarchical exclusive scan of in-degrees -> col_ptr ----------------
__launch_bounds__(SCB)
__global__ void scan_part(const int* __restrict__ deg, int* __restrict__ bsum) {
    __shared__ int s[SCB];
    int i = blockIdx.x * SCB + threadIdx.x;
    s[threadIdx.x] = (i < NN) ? deg[i] : 0;
    __syncthreads();
    for (int off = SCB / 2; off > 0; off >>= 1) {
        if (threadIdx.x < off) s[threadIdx.x] += s[threadIdx.x + off];
        __syncthreads();
    }
    if (threadIdx.x == 0) bsum[blockIdx.x] = s[0];
}

__launch_bounds__(SCB)
__global__ void scan_top(const int* __restrict__ bsum, int* __restrict__ boff) {
    __shared__ int s[SCB];
    const int tid = threadIdx.x;
    int v = (tid < NSCB) ? bsum[tid] : 0;
    s[tid] = v;
    __syncthreads();
    for (int off = 1; off < SCB; off <<= 1) {
        int t = (tid >= off) ? s[tid - off] : 0;
        __syncthreads();
        s[tid] += t;
        __syncthreads();
    }
    if (tid < NSCB) boff[tid] = s[tid] - v;   // exclusive
}

__launch_bounds__(SCB)
__global__ void scan_fin(const int* __restrict__ deg, const int* __restrict__ boff,
                         int* __restrict__ ptr, int* __restrict__ cursor) {
    __shared__ int s[SCB];
    const int tid = threadIdx.x;
    int i = blockIdx.x * SCB + tid;
    int v = (i < NN) ? deg[i] : 0;
    s[tid] = v;
    __syncthreads();
    for (int off = 1; off < SCB; off <<= 1) {
        int t = (tid >= off) ? s[tid - off] : 0;
        __syncthreads();
        s[tid] += t;
        __syncthreads();
    }
    if (i < NN) {
        int e = boff[blockIdx.x] + s[tid] - v;
        ptr[i] = e;
        cursor[i] = e;
    }
    if (i == 0) ptr[NN] = NE;
}

// fill dst-sorted edge list
__global__ void fill_kernel(const int* __restrict__ src, const int* __restrict__ dst,
                            int* __restrict__ cursor, int* __restrict__ esrc) {
    int e = blockIdx.x * blockDim.x + threadIdx.x;
    if (e >= NE) return;
    int p = atomicAdd(&cursor[dst[e]], 1);
    esrc[p] = src[e];
}

// ---------------- W transpose + fp16 convert: Wt[c][k] = (half)W[k][c] ----------------
__global__ void wt_kernel(const float* __restrict__ W1, const float* __restrict__ W2,
                          __half* __restrict__ Wt1, __half* __restrict__ Wt2) {
    if (blockIdx.x == 0) {
        for (int e = threadIdx.x; e < KF * OC1; e += 256) {
            int k = e >> 7, c = e & (OC1 - 1);
            Wt1[c * KF + k] = __float2half(W1[e]);
        }
    } else {
        for (int e = threadIdx.x; e < KF * OC2; e += 256) {
            int k = e >> 6, c = e & (OC2 - 1);
            Wt2[c * KF + k] = __float2half(W2[e]);
        }
    }
}

// ---------------- MFMA GEMM: g[r] = fp16( nsrc[r] * (A[r] @ W) ) ----------------
// A: [NN, KF] (f32 or f16), Wt: [OC][KF] f16 (pre-transposed), g: [NN, OC] f16.
// Block: 256 threads (4 waves), 64-row tile. Wave w owns rows [16w,16w+16) x all OC cols.
// v_mfma_f32_16x16x32_f16: A-frag row=lane&15, k=(lane>>4)*8+j; B-frag col=lane&15 (same k);
// C/D col=lane&15, row=(lane>>4)*4+reg  [m89-verified layout].
template <int OC, typename AT>
__launch_bounds__(256)
__global__ void gemm_mfma(const AT* __restrict__ A, const __half* __restrict__ Wt,
                          const float* __restrict__ nsrc, __half* __restrict__ g) {
    constexpr int LDK = KF + 8;          // 136 halves = 272 B row stride (16B-aligned, 4-bank shift)
    constexpr int NT = OC / 16;          // col tiles per wave: 8 or 4
    __shared__ _Float16 Ash[64 * LDK];   // 17.4 KB
    __shared__ _Float16 Wsh[OC * LDK];   // 34.8 / 17.4 KB

    const int tid = threadIdx.x;
    const int row0 = blockIdx.x * 64;

    // stage A (convert f32 -> f16 if needed); 64 rows x 128 cols, 4 elems/thread/iter
    for (int i = tid; i < 64 * (KF / 4); i += 256) {
        int r = i >> 5;                 // KF/4 == 32
        int c4 = i & 31;
        int grow = row0 + r;
        if constexpr (sizeof(AT) == 4) {
            float4 v = make_float4(0.f, 0.f, 0.f, 0.f);
            if (grow < NN) v = reinterpret_cast<const float4*>(A + (size_t)grow * KF)[c4];
            __half2* dp = reinterpret_cast<__half2*>(&Ash[r * LDK + c4 * 4]);
            dp[0] = __floats2half2_rn(v.x, v.y);
            dp[1] = __floats2half2_rn(v.z, v.w);
        } else {
            uint2 u = make_uint2(0u, 0u);
            if (grow < NN) u = reinterpret_cast<const uint2*>(A + (size_t)grow * KF)[c4];
            *reinterpret_cast<uint2*>(&Ash[r * LDK + c4 * 4]) = u;
        }
    }
    // stage Wt (already f16, coalesced rows)
    for (int i = tid; i < OC * (KF / 4); i += 256) {
        int r = i >> 5;
        int c4 = i & 31;
        *reinterpret_cast<uint2*>(&Wsh[r * LDK + c4 * 4]) =
            reinterpret_cast<const uint2*>(Wt + (size_t)r * KF)[c4];
    }
    __syncthreads();

    const int wave = tid >> 6;
    const int lane = tid & 63;
    const int arow = wave * 16 + (lane & 15);
    const int koff = (lane >> 4) * 8;

    half8 afr[4];
#pragma unroll
    for (int kk = 0; kk < 4; kk++)
        afr[kk] = *reinterpret_cast<const half8*>(&Ash[arow * LDK + kk * 32 + koff]);

    floatx4 acc[NT];
#pragma unroll
    for (int n = 0; n < NT; n++) acc[n] = (floatx4)(0.f);

#pragma unroll
    for (int n = 0; n < NT; n++) {
        const int bcol = n * 16 + (lane & 15);
#pragma unroll
        for (int kk = 0; kk < 4; kk++) {
            half8 bfr = *reinterpret_cast<const half8*>(&Wsh[bcol * LDK + kk * 32 + koff]);
            acc[n] = __builtin_amdgcn_mfma_f32_16x16x32_f16(afr[kk], bfr, acc[n], 0, 0, 0);
        }
    }

    // epilogue: scale by nsrc, convert fp16, scatter-store (2B each)
    const int crow = row0 + wave * 16 + (lane >> 4) * 4;
    const int col = lane & 15;
    float nsv[4];
#pragma unroll
    for (int j = 0; j < 4; j++) {
        int rr = crow + j;
        nsv[j] = (rr < NN) ? nsrc[rr] : 0.f;
    }
#pragma unroll
    for (int n = 0; n < NT; n++) {
#pragma unroll
        for (int j = 0; j < 4; j++) {
            int rr = crow + j;
            if (rr < NN)
                g[(size_t)rr * OC + n * 16 + col] = __float2half(acc[n][j] * nsv[j]);
        }
    }
}

// ---------------- gather (OC=128): h1[d] = fp16(relu(ndst*sum g[esrc] + b)) ----------------
__launch_bounds__(256)
__global__ void gather128_kernel(const __half2* __restrict__ g, const int* __restrict__ ptr,
                                 const int* __restrict__ esrc, const float* __restrict__ ndst,
                                 const float* __restrict__ b, __half2* __restrict__ h1) {
    const int node = blockIdx.x * 4 + (threadIdx.x >> 6);
    if (node >= NN) return;
    const int lane = threadIdx.x & 63;
    const int lo = ptr[node];
    const int hi = ptr[node + 1];
    const float nd = ndst[node];

    float2 a[8];
#pragma unroll
    for (int i = 0; i < 8; i++) a[i] = make_float2(0.f, 0.f);

    int e = lo;
    for (; e + 7 < hi; e += 8) {
        int s[8];
#pragma unroll
        for (int i = 0; i < 8; i++) s[i] = esrc[e + i];
#pragma unroll
        for (int i = 0; i < 8; i++) {
            float2 v = __half22float2(g[(size_t)s[i] * 64 + lane]);
            a[i].x += v.x; a[i].y += v.y;
        }
    }
    for (; e < hi; e++) {
        float2 v = __half22float2(g[(size_t)esrc[e] * 64 + lane]);
        a[0].x += v.x; a[0].y += v.y;
    }
#pragma unroll
    for (int i = 1; i < 8; i++) { a[0].x += a[i].x; a[0].y += a[i].y; }

    float2 bb = reinterpret_cast<const float2*>(b)[lane];
    float ox = fmaxf(fmaf(a[0].x, nd, bb.x), 0.f);
    float oy = fmaxf(fmaf(a[0].y, nd, bb.y), 0.f);
    h1[(size_t)node * 64 + lane] = __floats2half2_rn(ox, oy);
}

// ---------------- gather (OC=64): out[d] = f32(ndst*sum g[esrc] + b) ----------------
__launch_bounds__(256)
__global__ void gather64_kernel(const __half2* __restrict__ g, const int* __restrict__ ptr,
                                const int* __restrict__ esrc, const float* __restrict__ ndst,
                                const float* __restrict__ b, float* __restrict__ out) {
    const int node = blockIdx.x * 4 + (threadIdx.x >> 6);
    if (node >= NN) return;
    const int lane = threadIdx.x & 63;
    const int l32 = lane & 31;
    const int half_id = lane >> 5;
    const int lo = ptr[node];
    const int hi = ptr[node + 1];
    const float nd = ndst[node];

    float2 a[4];
#pragma unroll
    for (int i = 0; i < 4; i++) a[i] = make_float2(0.f, 0.f);

    int e = lo + half_id;
    for (; e + 6 < hi; e += 8) {
        int s[4];
#pragma unroll
        for (int i = 0; i < 4; i++) s[i] = esrc[e + 2 * i];
#pragma unroll
        for (int i = 0; i < 4; i++) {
            float2 v = __half22float2(g[(size_t)s[i] * 32 + l32]);
            a[i].x += v.x; a[i].y += v.y;
        }
    }
    for (; e < hi; e += 2) {
        float2 v = __half22float2(g[(size_t)esrc[e] * 32 + l32]);
        a[0].x += v.x; a[0].y += v.y;
    }
#pragma unroll
    for (int i = 1; i < 4; i++) { a[0].x += a[i].x; a[0].y += a[i].y; }

    a[0].x += __shfl_xor(a[0].x, 32);
    a[0].y += __shfl_xor(a[0].y, 32);
    if (half_id == 0) {
        float2 bb = reinterpret_cast<const float2*>(b)[l32];
        float2 o = make_float2(fmaf(a[0].x, nd, bb.x), fmaf(a[0].y, nd, bb.y));
        reinterpret_cast<float2*>(out + (size_t)node * 64)[l32] = o;
    }
}

extern "C" void kernel_launch(void* const* d_in, const int* in_sizes, int n_in,
                              void* d_out, int out_size, void* d_ws, size_t ws_size,
                              hipStream_t stream) {
    const float* x  = (const float*)d_in[0];   // [NN, 128]
    const float* W1 = (const float*)d_in[1];   // [128, 128]
    const float* b1 = (const float*)d_in[2];   // [128]
    const float* W2 = (const float*)d_in[3];   // [128, 64]
    const float* b2 = (const float*)d_in[4];   // [64]
    const int*   src = (const int*)d_in[5];    // [NE]
    const int*   dst = (const int*)d_in[6];    // [NE]
    float* out = (float*)d_out;                // [NN, 64]

    float*  nsrc = (float*)d_ws;                     // NN
    float*  ndst = nsrc + NN;                        // NN
    __half* g    = (__half*)(ndst + NN);             // NN*128 f16 (layer 2 uses NN*64)
    __half* h1   = g + (size_t)NN * KF;              // NN*128 f16
    int* deg_i  = (int*)(h1 + (size_t)NN * KF);      // NN
    int* ptr    = deg_i + NN;                        // NN+1
    int* cursor = ptr + NN + 1;                      // NN
    int* esrc   = cursor + NN;                       // NE
    int* bsum   = esrc + NE;                         // NSCB
    int* boff   = bsum + NSCB;                       // NSCB
    int* Hs     = boff + NSCB;                       // HBLK*HP  (6.4 MB)
    int* Hd     = Hs + (size_t)HBLK * HP;            // HBLK*HP  (6.4 MB)
    __half* Wt1 = (__half*)(Hd + (size_t)HBLK * HP); // 128*128 f16
    __half* Wt2 = Wt1 + KF * OC1;                    // 64*128 f16

    // W transpose+convert; degrees; CSC build
    wt_kernel<<<2, 256, 0, stream>>>(W1, W2, Wt1, Wt2);
    hist16_kernel<<<2 * HBLK, 256, 0, stream>>>(src, dst, Hs, Hd);
    rednorm_kernel<<<(HP + 255) / 256, 256, 0, stream>>>(Hs, Hd, deg_i, nsrc, ndst);
    scan_part<<<NSCB, SCB, 0, stream>>>(deg_i, bsum);
    scan_top<<<1, SCB, 0, stream>>>(bsum, boff);
    scan_fin<<<NSCB, SCB, 0, stream>>>(deg_i, boff, ptr, cursor);
    fill_kernel<<<(NE + 255) / 256, 256, 0, stream>>>(src, dst, cursor, esrc);

    // layer 1: g = fp16(nsrc * (x @ W1)); h1 = fp16(relu(ndst * gather(g) + b1))
    gemm_mfma<OC1, float><<<(NN + 63) / 64, 256, 0, stream>>>(x, Wt1, nsrc, g);
    gather128_kernel<<<(NN + 3) / 4, 256, 0, stream>>>((const __half2*)g, ptr, esrc, ndst, b1,
                                                       (__half2*)h1);

    // layer 2: g = fp16(nsrc * (h1 @ W2)); out = ndst * gather(g) + b2
    gemm_mfma<OC2, __half><<<(NN + 63) / 64, 256, 0, stream>>>(h1, Wt2, nsrc, g);
    gather64_kernel<<<(NN + 3) / 4, 256, 0, stream>>>((const __half2*)g, ptr, esrc, ndst, b2, out);
}